// Round 8
// baseline (1482.863 us; speedup 1.0000x reference)
//
#include <hip/hip_runtime.h>
#include <hip/hip_bf16.h>
#include <math.h>

// ---------------------------------------------------------------------------
// SimpleMoEModel: dense GEMM -> top1-MoE -> top1-MoE -> residual -> mean ->
// log_softmax -> NLL.  B=8 S=2048 D=1024 E=8, capacity = T/E = 2048.
//
// Round 8: ONE persistent mega-kernel (1024 blocks = 4/CU, co-resident by
// construction: LDS 32 KB -> 5 blocks/CU cap, __launch_bounds__(256,4) caps
// VGPR at 128) with soft grid barriers (device-scope atomics + __threadfence
// for cross-XCD L2 flush/inv, G16). Eliminates ~14 dispatch boundaries
// (~10 us each - the dominant cost per r7 accounting). Stage bodies are
// r5-verified verbatim; GEMM epilogues lean (r6/r7 lesson: logit fusion into
// GEMM epilogues costs an unhidden ~20 us serial tail - atomics at the end of
// a block have nothing to overlap).
// Stages: prep | dense(+sent-h) | gate2 | route2 | expert2 | gate3 | route3 |
//         expert3 | reduce(o2) | loss.  9 barriers.
// ---------------------------------------------------------------------------

#define TOKS 16384
#define DIM 1024
#define NEXP 8
#define CAP 2048
#define BATCH 8
#define SEQ 2048
#define NBLK 1024

typedef __bf16 bf16_t;
typedef __bf16 bf16x8 __attribute__((ext_vector_type(8)));
typedef float fx4 __attribute__((ext_vector_type(4)));

__device__ __forceinline__ void gll16(const bf16_t* g, bf16_t* l) {
  __builtin_amdgcn_global_load_lds(
      (const __attribute__((address_space(1))) unsigned int*)g,
      (__attribute__((address_space(3))) unsigned int*)l, 16, 0, 0);
}

// ---- soft grid barrier: bars[0]=count, bars[1]=generation (memset to 0) ---
// Spin uses RELAXED atomic loads (no per-poll cache inv); the single
// __threadfence() on exit does the agent-scope acquire (L1/L2 inv), the one
// before arrival does the release (L2 writeback) -> cross-XCD coherent.
__device__ __forceinline__ void gbar(int* bars) {
  __syncthreads();
  if (threadIdx.x == 0) {
    __threadfence();  // release: flush this block's dirty L2 before arriving
    int gen = __hip_atomic_load(&bars[1], __ATOMIC_RELAXED, __HIP_MEMORY_SCOPE_AGENT);
    int prev = __hip_atomic_fetch_add(&bars[0], 1, __ATOMIC_RELAXED, __HIP_MEMORY_SCOPE_AGENT);
    if (prev == NBLK - 1) {
      __hip_atomic_store(&bars[0], 0, __ATOMIC_RELAXED, __HIP_MEMORY_SCOPE_AGENT);
      __threadfence();  // order count reset before gen bump
      __hip_atomic_store(&bars[1], gen + 1, __ATOMIC_RELAXED, __HIP_MEMORY_SCOPE_AGENT);
    } else {
      while (__hip_atomic_load(&bars[1], __ATOMIC_RELAXED, __HIP_MEMORY_SCOPE_AGENT) == gen)
        __builtin_amdgcn_s_sleep(2);
    }
    __threadfence();  // acquire: invalidate stale L1/L2 before next stage
  }
  __syncthreads();
}

// ---------------- stage: prep (grid-stride jobs over 1024 blocks) ----------
// jobs 0..4351: W transpose tiles; 4352..4353: Wg packs; rest: x cvt chunks.
#define NJOB_W (17 * 256)
#define NJOB_CVT (TOKS * DIM / 8 / 256)
#define NJOBS (NJOB_W + 2 + NJOB_CVT)
__device__ void st_prep(int id, const float* W1, const float* We2,
                        const float* We3, const float* Wg2, const float* Wg3,
                        const float* x, bf16_t* Wt, bf16_t* WgP, bf16_t* xb,
                        char* smraw) {
  const int tid = threadIdx.x;
  for (int job = id; job < NJOBS; job += NBLK) {
    if (job < NJOB_W) {
      float(*t)[65] = (float(*)[65])smraw;
      const int m = job >> 8, rem = job & 255;
      const int n0 = (rem & 15) * 64, k0 = (rem >> 4) * 64;
      const float* src = (m == 0) ? W1
                         : (m <= 8) ? We2 + (size_t)(m - 1) * DIM * DIM
                                    : We3 + (size_t)(m - 9) * DIM * DIM;
      bf16_t* dst = Wt + (size_t)m * DIM * DIM;
      const int r = tid >> 4, c4 = (tid & 15) * 4;
#pragma unroll
      for (int i = 0; i < 4; i++) {
        float4 v = *(const float4*)&src[(size_t)(k0 + i * 16 + r) * DIM + n0 + c4];
        t[i * 16 + r][c4] = v.x;
        t[i * 16 + r][c4 + 1] = v.y;
        t[i * 16 + r][c4 + 2] = v.z;
        t[i * 16 + r][c4 + 3] = v.w;
      }
      __syncthreads();
#pragma unroll
      for (int i = 0; i < 4; i++) {
        int rn = i * 16 + r;
        union { bf16_t b[4]; uint2 u; } tmp;
#pragma unroll
        for (int j = 0; j < 4; j++) tmp.b[j] = (bf16_t)t[c4 + j][rn];
        *(uint2*)&dst[(size_t)(n0 + rn) * DIM + k0 + c4] = tmp.u;
      }
      __syncthreads();  // tile buffer reused next job
    } else if (job < NJOB_W + 2) {
      const int which = job - NJOB_W;
      const float* src = which ? Wg3 : Wg2;
      bf16_t* dst = WgP + which * (128 * 8 * 8);
#pragma unroll
      for (int j = 0; j < 4; j++) {
        int d = tid * 4 + j;
        float4 a = *(const float4*)&src[d * 8];
        float4 b = *(const float4*)&src[d * 8 + 4];
        float v[8] = {a.x, a.y, a.z, a.w, b.x, b.y, b.z, b.w};
#pragma unroll
        for (int e = 0; e < 8; e++)
          dst[((d >> 3) * 8 + e) * 8 + (d & 7)] = (bf16_t)v[e];
      }
    } else {
      const int cid = job - NJOB_W - 2;
      size_t i = ((size_t)cid * 256 + tid) * 8;
      float4 a = *(const float4*)&x[i];
      float4 b = *(const float4*)&x[i + 4];
      union { bf16_t h[8]; uint4 u; } t;
      t.h[0] = (bf16_t)a.x; t.h[1] = (bf16_t)a.y; t.h[2] = (bf16_t)a.z; t.h[3] = (bf16_t)a.w;
      t.h[4] = (bf16_t)b.x; t.h[5] = (bf16_t)b.y; t.h[6] = (bf16_t)b.z; t.h[7] = (bf16_t)b.w;
      *(uint4*)&xb[i] = t.u;
    }
  }
}

// ---------------- stage: dense GEMM h = xb@W1t + b1, + sent(h) -------------
__device__ void st_dense(int id, const bf16_t* A, const bf16_t* Bt,
                         const float* bias, bf16_t* out, float* sent,
                         char* smraw) {
  bf16_t* As = (bf16_t*)smraw;
  bf16_t* Bs = As + 128 * 64;
  const int tid = threadIdx.x;
  const int lane = tid & 63, wave = tid >> 6;
  const int quad = lane >> 4, l15 = lane & 15;
  const int wr = (wave >> 1) * 64, wc = (wave & 1) * 64;
  const int j_ = id >> 3;
  const int m0 = ((id & 7) * 16 + (j_ >> 3)) * 128;  // XCD-aware decode
  const int n0 = (j_ & 7) * 128;
  const int kc = (tid & 7) ^ ((tid >> 3) & 7);
  const int rbase = tid >> 3;

  const bf16_t* gA[4]; const bf16_t* gB[4]; bf16_t* lA[4]; bf16_t* lB[4];
#pragma unroll
  for (int i = 0; i < 4; i++) {
    int r = rbase + 32 * i;
    gA[i] = A + (size_t)(m0 + r) * DIM + kc * 8;
    gB[i] = Bt + (size_t)(n0 + r) * DIM + kc * 8;
    lA[i] = &As[(wave * 64 + 256 * i) * 8];
    lB[i] = &Bs[(wave * 64 + 256 * i) * 8];
  }
  fx4 acc[4][4];
#pragma unroll
  for (int i = 0; i < 4; i++)
#pragma unroll
    for (int j = 0; j < 4; j++) acc[i][j] = (fx4)0.0f;

  for (int k0 = 0; k0 < DIM; k0 += 64) {
#pragma unroll
    for (int i = 0; i < 4; i++) gll16(gA[i] + k0, lA[i]);
#pragma unroll
    for (int i = 0; i < 4; i++) gll16(gB[i] + k0, lB[i]);
    __syncthreads();
#pragma unroll
    for (int s = 0; s < 2; s++) {
      const int pofs = ((s * 4 + quad) ^ (l15 & 7)) << 3;
      bf16x8 av[4], bv[4];
#pragma unroll
      for (int i = 0; i < 4; i++)
        av[i] = *(const bf16x8*)&As[(wr + i * 16 + l15) * 64 + pofs];
#pragma unroll
      for (int j = 0; j < 4; j++)
        bv[j] = *(const bf16x8*)&Bs[(wc + j * 16 + l15) * 64 + pofs];
#pragma unroll
      for (int i = 0; i < 4; i++)
#pragma unroll
        for (int j = 0; j < 4; j++)
          acc[i][j] = __builtin_amdgcn_mfma_f32_16x16x32_bf16(av[i], bv[j], acc[i][j], 0, 0, 0);
    }
    __syncthreads();
  }
  float bb[4], sj[4] = {0.f, 0.f, 0.f, 0.f};
#pragma unroll
  for (int j = 0; j < 4; j++) bb[j] = bias[n0 + wc + j * 16 + l15];
#pragma unroll
  for (int i = 0; i < 4; i++)
#pragma unroll
    for (int r = 0; r < 4; r++) {
      int rowL = wr + i * 16 + quad * 4 + r;  // C/D layout (m89/m91)
#pragma unroll
      for (int j = 0; j < 4; j++) {
        float v = acc[i][j][r] + bb[j];
        sj[j] += v;
        out[(size_t)(m0 + rowL) * DIM + n0 + wc + j * 16 + l15] = (bf16_t)v;
      }
    }
  // sent(h): tile rows are batch-uniform (2048 rows/batch, 128-row tiles)
#pragma unroll
  for (int j = 0; j < 4; j++) {
    sj[j] += __shfl_xor(sj[j], 16);
    sj[j] += __shfl_xor(sj[j], 32);
  }
  if (quad == 0) {
#pragma unroll
    for (int j = 0; j < 4; j++)
      atomicAdd(&sent[(m0 >> 11) * DIM + n0 + wc + j * 16 + l15],
                sj[j] * (1.0f / SEQ));
  }
}

// ---------------- stage: MFMA gating (r5-verified) -------------------------
__device__ void st_gate(int id, const bf16_t* act, const bf16_t* WgPx,
                        int* idx, float* gate, char* smraw) {
  if (id >= 256) return;
  bf16_t* As = (bf16_t*)smraw;           // 64x64 = 8 KB
  bf16_t* WgS = As + 64 * 64;            // 128x64 = 16 KB
  float* L = (float*)(WgS + 128 * 64);   // 64x8 = 2 KB
  const int tid = threadIdx.x;
  const int lane = tid & 63, wave = tid >> 6;
  const int quad = lane >> 4, l15 = lane & 15;
  const int m0 = id * 64;
  const int kc = (tid & 7) ^ ((tid >> 3) & 7);
  const int rbase = tid >> 3;

  // per-lane global addresses (m104/m108 - r4 lesson)
#pragma unroll
  for (int j = 0; j < 4; j++)
    gll16(WgPx + (j * 256 + wave * 64 + lane) * 8, &WgS[(j * 256 + wave * 64) * 8]);

  const bf16_t* gA[2]; bf16_t* lA[2];
#pragma unroll
  for (int i = 0; i < 2; i++) {
    gA[i] = act + (size_t)(m0 + rbase + 32 * i) * DIM + kc * 8;
    lA[i] = &As[wave * 512 + i * 2048];
  }
  fx4 acc = (fx4)0.0f;
  for (int k0 = 0; k0 < DIM; k0 += 64) {
#pragma unroll
    for (int i = 0; i < 2; i++) gll16(gA[i] + k0, lA[i]);
    __syncthreads();
#pragma unroll
    for (int s = 0; s < 2; s++) {
      const int pofs = ((s * 4 + quad) ^ (l15 & 7)) << 3;
      bf16x8 av = *(const bf16x8*)&As[(wave * 16 + l15) * 64 + pofs];
      bf16x8 bv = *(const bf16x8*)&WgS[((k0 >> 3) + s * 4 + quad) * 64 + (l15 & 7) * 8];
      acc = __builtin_amdgcn_mfma_f32_16x16x32_bf16(av, bv, acc, 0, 0, 0);
    }
    __syncthreads();
  }
  if (l15 < 8) {
#pragma unroll
    for (int r = 0; r < 4; r++) L[(wave * 16 + quad * 4 + r) * 8 + l15] = acc[r];
  }
  __syncthreads();
  if (tid < 64) {
    float lg[8];
#pragma unroll
    for (int e = 0; e < 8; e++) lg[e] = L[tid * 8 + e];
    float best = lg[0];
    int bi = 0;
#pragma unroll
    for (int e = 1; e < 8; e++)
      if (lg[e] > best) { best = lg[e]; bi = e; }  // strict >: first max wins
    float s = 0.f;
#pragma unroll
    for (int e = 0; e < 8; e++) s += expf(lg[e] - best);
    idx[m0 + tid] = bi;
    gate[m0 + tid] = 1.0f / s;
  }
}

// ---------------- stage: route (8 blocks; 256 thr x 64 tokens, bitmask) ----
#define DLMAX 2048
__device__ void st_route(int id, const int* idx, int* tok, int* cnt,
                         bf16_t* obuf, char* smraw) {
  if (id >= 8) return;
  int* wsum = (int*)smraw;        // 4 waves
  int* dlist = wsum + 16;         // 2048 drops max
  const int e = id;
  const int tid = threadIdx.x, lane = tid & 63, wv = tid >> 6;
  const int4* p4 = (const int4*)(idx + tid * 64);
  unsigned long long mask = 0ull;
#pragma unroll 4
  for (int j = 0; j < 16; j++) {
    int4 v = p4[j];
    mask |= (unsigned long long)(v.x == e) << (4 * j);
    mask |= (unsigned long long)(v.y == e) << (4 * j + 1);
    mask |= (unsigned long long)(v.z == e) << (4 * j + 2);
    mask |= (unsigned long long)(v.w == e) << (4 * j + 3);
  }
  int c = __popcll(mask);
  int sc = c;
#pragma unroll
  for (int off = 1; off < 64; off <<= 1) {
    int n = __shfl_up(sc, off);
    if (lane >= off) sc += n;
  }
  if (lane == 63) wsum[wv] = sc;
  __syncthreads();
  int wb = 0, tot = 0;
#pragma unroll
  for (int i = 0; i < 4; i++) {
    int s = wsum[i];
    tot += s;
    if (i < wv) wb += s;
  }
  int pos = wb + sc - c;  // exclusive prefix
  const uint4 z = {0u, 0u, 0u, 0u};
  for (int j = 0; j < 64; j++) {
    if ((mask >> j) & 1ull) {
      int t = tid * 64 + j;
      if (pos < CAP) {
        tok[e * CAP + pos] = t;
      } else {
        int di = pos - CAP;
        if (di < DLMAX) dlist[di] = t;
        else
          for (int k = 0; k < 128; k++) *(uint4*)&obuf[(size_t)t * DIM + k * 8] = z;
      }
      pos++;
    }
  }
  if (tid == 0) cnt[e] = tot < CAP ? tot : CAP;
  __syncthreads();
  int ndl = tot - CAP;
  ndl = ndl < 0 ? 0 : (ndl > DLMAX ? DLMAX : ndl);
  for (int d = tid >> 7; d < ndl; d += 2) {  // 128 thr/row, 2 rows at a time
    int t = dlist[d];
    *(uint4*)&obuf[(size_t)t * DIM + (tid & 127) * 8] = z;
  }
}

// ---------------- stage: expert GEMM (r5-verified, lean epilogue) ----------
__device__ void st_expert(int id, const bf16_t* Ain, const bf16_t* Wt8,
                          const float* be, const int* tok, const int* cnt,
                          const float* gate, const bf16_t* zp,
                          bf16_t* outp, char* smraw) {
  const int e = id & 7;  // XCD-aware: expert = XCD slot (weights L2-resident)
  const int j_ = id >> 3;
  const int c0 = (j_ >> 3) * 128;
  const int n0 = (j_ & 7) * 128;
  const int count = cnt[e];
  if (c0 >= count) return;
  const bf16_t* Bt = Wt8 + (size_t)e * DIM * DIM;
  const float* bias = be + (size_t)e * DIM;
  const int* tk = tok + e * CAP;

  bf16_t* As = (bf16_t*)smraw;
  bf16_t* Bs = As + 128 * 64;
  const int tid = threadIdx.x;
  const int lane = tid & 63, wave = tid >> 6;
  const int quad = lane >> 4, l15 = lane & 15;
  const int wr = (wave >> 1) * 64, wc = (wave & 1) * 64;
  const int kc = (tid & 7) ^ ((tid >> 3) & 7);
  const int rbase = tid >> 3;

  const bf16_t* gA[4]; const bf16_t* gB[4]; bf16_t* lA[4]; bf16_t* lB[4];
#pragma unroll
  for (int i = 0; i < 4; i++) {
    int r = rbase + 32 * i;
    int ca = c0 + r;
    gA[i] = (ca < count) ? Ain + (size_t)tk[ca] * DIM + kc * 8 : zp;
    gB[i] = Bt + (size_t)(n0 + r) * DIM + kc * 8;
    lA[i] = &As[(wave * 64 + 256 * i) * 8];
    lB[i] = &Bs[(wave * 64 + 256 * i) * 8];
  }
  fx4 acc[4][4];
#pragma unroll
  for (int i = 0; i < 4; i++)
#pragma unroll
    for (int j = 0; j < 4; j++) acc[i][j] = (fx4)0.0f;

  for (int k0 = 0; k0 < DIM; k0 += 64) {
#pragma unroll
    for (int i = 0; i < 4; i++) gll16(gA[i] + k0, lA[i]);
#pragma unroll
    for (int i = 0; i < 4; i++) gll16(gB[i] + k0, lB[i]);
    __syncthreads();
#pragma unroll
    for (int s = 0; s < 2; s++) {
      const int pofs = ((s * 4 + quad) ^ (l15 & 7)) << 3;
      bf16x8 av[4], bv[4];
#pragma unroll
      for (int i = 0; i < 4; i++)
        av[i] = *(const bf16x8*)&As[(wr + i * 16 + l15) * 64 + pofs];
#pragma unroll
      for (int j = 0; j < 4; j++)
        bv[j] = *(const bf16x8*)&Bs[(wc + j * 16 + l15) * 64 + pofs];
#pragma unroll
      for (int i = 0; i < 4; i++)
#pragma unroll
        for (int j = 0; j < 4; j++)
          acc[i][j] = __builtin_amdgcn_mfma_f32_16x16x32_bf16(av[i], bv[j], acc[i][j], 0, 0, 0);
    }
    __syncthreads();
  }
  float bb[4];
#pragma unroll
  for (int j = 0; j < 4; j++) bb[j] = bias[n0 + wc + j * 16 + l15];
#pragma unroll
  for (int i = 0; i < 4; i++)
#pragma unroll
    for (int r = 0; r < 4; r++) {
      int c = c0 + wr + i * 16 + quad * 4 + r;
      if (c < count) {
        int t = tk[c];
        float g = gate[t];
#pragma unroll
        for (int j = 0; j < 4; j++)
          outp[(size_t)t * DIM + n0 + wc + j * 16 + l15] =
              (bf16_t)((acc[i][j][r] + bb[j]) * g);
      }
    }
}

// ---------------- stage: sent += mean_s(o2) --------------------------------
__device__ void st_reduce(int id, const bf16_t* o2, float* sent) {
  if (id >= 256) return;
  const int tid = threadIdx.x;
  const int d8 = (tid & 127) * 8;
  const int sg = tid >> 7;
  const int b = id >> 5;
  const int s0 = (id & 31) * 64 + sg * 32;
  float acc[8] = {0.f, 0.f, 0.f, 0.f, 0.f, 0.f, 0.f, 0.f};
  const size_t base = ((size_t)b * SEQ + s0) * DIM + d8;
  for (int i = 0; i < 32; i++) {
    union { bf16_t v[8]; uint4 u; } oo;
    oo.u = *(const uint4*)&o2[base + (size_t)i * DIM];
#pragma unroll
    for (int j = 0; j < 8; j++) acc[j] += (float)oo.v[j];
  }
#pragma unroll
  for (int j = 0; j < 8; j++)
    atomicAdd(&sent[b * DIM + d8 + j], acc[j] * (1.0f / SEQ));
}

// ---------------- stage: loss ----------------------------------------------
__device__ void st_loss(int id, const float* sent, const int* y, float* out,
                        char* smraw) {
  if (id >= 8) return;
  float* red = (float*)smraw;
  const int b = id, tid = threadIdx.x;
  const float* sb = sent + b * DIM;
  float m = -1e30f;
  for (int d = tid; d < DIM; d += 256) m = fmaxf(m, sb[d]);
  red[tid] = m;
  __syncthreads();
  for (int s = 128; s; s >>= 1) {
    if (tid < s) red[tid] = fmaxf(red[tid], red[tid + s]);
    __syncthreads();
  }
  m = red[0];
  __syncthreads();
  float sum = 0.f;
  for (int d = tid; d < DIM; d += 256) sum += expf(sb[d] - m);
  red[tid] = sum;
  __syncthreads();
  for (int s = 128; s; s >>= 1) {
    if (tid < s) red[tid] += red[tid + s];
    __syncthreads();
  }
  if (tid == 0) atomicAdd(out, (m + logf(red[0]) - sb[y[b]]) * (1.0f / BATCH));
}

// ---------------- the mega-kernel ------------------------------------------
__global__ __launch_bounds__(256, 4) void k_mega(
    const float* W1, const float* We2, const float* We3, const float* Wg2,
    const float* Wg3, const float* x, const float* b1, const float* be2,
    const float* be3, const int* y, bf16_t* Wt, bf16_t* WgP, bf16_t* xb,
    bf16_t* h, bf16_t* o1, bf16_t* o2, int* idx, float* gate, int* tok,
    int* cnt, float* sent, bf16_t* zp, int* bars, float* dout) {
  __shared__ alignas(16) char smraw[32768];
  const int id = blockIdx.x;

  st_prep(id, W1, We2, We3, Wg2, Wg3, x, Wt, WgP, xb, smraw);
  gbar(bars);
  st_dense(id, xb, Wt, b1, h, sent, smraw);
  gbar(bars);
  st_gate(id, h, WgP, idx, gate, smraw);
  gbar(bars);
  st_route(id, idx, tok, cnt, o1, smraw);
  gbar(bars);
  st_expert(id, h, Wt + (size_t)1 * DIM * DIM, be2, tok, cnt, gate, zp, o1, smraw);
  gbar(bars);
  st_gate(id, o1, WgP + 128 * 8 * 8, idx, gate, smraw);
  gbar(bars);
  st_route(id, idx, tok, cnt, o2, smraw);
  gbar(bars);
  st_expert(id, o1, Wt + (size_t)9 * DIM * DIM, be3, tok, cnt, gate, zp, o2, smraw);
  gbar(bars);
  st_reduce(id, o2, sent);
  gbar(bars);
  st_loss(id, sent, y, dout, smraw);
}

// ---------------------------------------------------------------------------
extern "C" void kernel_launch(void* const* d_in, const int* in_sizes, int n_in,
                              void* d_out, int out_size, void* d_ws, size_t ws_size,
                              hipStream_t stream) {
  (void)in_sizes; (void)n_in; (void)out_size; (void)ws_size;
  const float* x   = (const float*)d_in[0];
  const int*   y   = (const int*)d_in[1];
  const float* W1  = (const float*)d_in[2];
  const float* b1  = (const float*)d_in[3];
  const float* Wg2 = (const float*)d_in[4];
  const float* We2 = (const float*)d_in[5];
  const float* be2 = (const float*)d_in[6];
  const float* Wg3 = (const float*)d_in[7];
  const float* We3 = (const float*)d_in[8];
  const float* be3 = (const float*)d_in[9];

  char* p = (char*)d_ws;
  size_t off = 0;
  auto carve = [&](size_t bytes) -> char* {
    char* r = p + off;
    off += (bytes + 255) & ~(size_t)255;
    return r;
  };
  bf16_t* Wt   = (bf16_t*)carve((size_t)17 * DIM * DIM * 2);  // 0:W1t 1..8:We2t 9..16:We3t
  bf16_t* WgP  = (bf16_t*)carve(2 * 128 * 8 * 8 * 2);         // gate B-frag packs
  bf16_t* h    = (bf16_t*)carve((size_t)TOKS * DIM * 2);
  bf16_t* o1   = (bf16_t*)carve((size_t)TOKS * DIM * 2);
  bf16_t* o2   = (bf16_t*)carve((size_t)TOKS * DIM * 2);  // aliases xb lifetime
  int*    idx  = (int*)carve(TOKS * 4);
  float*  gate = (float*)carve(TOKS * 4);
  int*    tok  = (int*)carve(NEXP * CAP * 4);
  int*    cnt  = (int*)carve(NEXP * 4);
  // --- contiguous zero region: sent, zp, barrier state (single memset) ---
  size_t zoff0 = off;
  float*  sent = (float*)carve(BATCH * DIM * 4);
  bf16_t* zp   = (bf16_t*)carve(4096);
  int*    bars = (int*)carve(256);
  size_t zbytes = off - zoff0;
  bf16_t* xb   = o2;  // x-bf16 dead before o2 is born (expert3/route3)

  hipMemsetAsync(sent, 0, zbytes, stream);  // sent + zp + bars
  hipMemsetAsync(d_out, 0, 4, stream);      // loss accumulates via atomics

  k_mega<<<NBLK, 256, 0, stream>>>(
      W1, We2, We3, Wg2, Wg3, x, b1, be2, be3, y, Wt, WgP, xb, h, o1, o2,
      idx, gate, tok, cnt, sent, zp, bars, (float*)d_out);
}

// Round 10
// 852.018 us; speedup vs baseline: 1.7404x; 1.7404x over previous
//
#include <hip/hip_runtime.h>
#include <hip/hip_bf16.h>
#include <math.h>

// ---------------------------------------------------------------------------
// SimpleMoEModel: dense GEMM -> top1-MoE -> top1-MoE -> residual -> mean ->
// log_softmax -> NLL.  B=8 S=2048 D=1024 E=8, capacity = T/E = 2048.
//
// Round 10: mega-kernel v3 (deadlock-proof by slack).
//  - r9 hung: grid == exact occupancy (zero slack) -> one stranded block ->
//    barrier deadlock. r8's clamp (256,4) spilled (VGPR 64 -> 487 MB scratch).
//  - Fix: grid = 512 (2/CU) with __launch_bounds__(256,2) (VGPR cap 256;
//    natural ~160 untouched -> no spill). Capacity at ~160 regs = 3/CU ->
//    768 slots >= 512 blocks = 1.5x slack -> co-residency guaranteed under
//    any dispatch skew. GEMM stages: exactly 2 tiles/block, balanced.
//  - Stage bodies identical to r8/r9 (r5-verified): prep | dense(+sent-h) |
//    gate2 | route2 | expert2 | gate3 | route3 | expert3 | reduce | loss,
//    soft grid barriers (relaxed-spin + threadfence, G16-safe).
// ---------------------------------------------------------------------------

#define TOKS 16384
#define DIM 1024
#define NEXP 8
#define CAP 2048
#define BATCH 8
#define SEQ 2048
#define NBLK 512

typedef __bf16 bf16_t;
typedef __bf16 bf16x8 __attribute__((ext_vector_type(8)));
typedef float fx4 __attribute__((ext_vector_type(4)));

__device__ __forceinline__ void gll16(const bf16_t* g, bf16_t* l) {
  __builtin_amdgcn_global_load_lds(
      (const __attribute__((address_space(1))) unsigned int*)g,
      (__attribute__((address_space(3))) unsigned int*)l, 16, 0, 0);
}

// ---- soft grid barrier: bars[0]=count, bars[1]=generation (memset to 0) ---
__device__ __forceinline__ void gbar(int* bars) {
  __syncthreads();
  if (threadIdx.x == 0) {
    __threadfence();  // release: flush dirty L2 before arrival
    int gen = __hip_atomic_load(&bars[1], __ATOMIC_RELAXED, __HIP_MEMORY_SCOPE_AGENT);
    int prev = __hip_atomic_fetch_add(&bars[0], 1, __ATOMIC_RELAXED, __HIP_MEMORY_SCOPE_AGENT);
    if (prev == NBLK - 1) {
      __hip_atomic_store(&bars[0], 0, __ATOMIC_RELAXED, __HIP_MEMORY_SCOPE_AGENT);
      __threadfence();
      __hip_atomic_store(&bars[1], gen + 1, __ATOMIC_RELAXED, __HIP_MEMORY_SCOPE_AGENT);
    } else {
      while (__hip_atomic_load(&bars[1], __ATOMIC_RELAXED, __HIP_MEMORY_SCOPE_AGENT) == gen)
        __builtin_amdgcn_s_sleep(2);
    }
    __threadfence();  // acquire: invalidate stale caches for next stage
  }
  __syncthreads();
}

// ---------------- stage: prep (grid-stride jobs) ---------------------------
#define NJOB_W (17 * 256)
#define NJOB_CVT (TOKS * DIM / 8 / 256)
#define NJOBS (NJOB_W + 2 + NJOB_CVT)
__device__ void st_prep(const float* W1, const float* We2, const float* We3,
                        const float* Wg2, const float* Wg3, const float* x,
                        bf16_t* Wt, bf16_t* WgP, bf16_t* xb, char* smraw) {
  const int tid = threadIdx.x;
  for (int job = blockIdx.x; job < NJOBS; job += NBLK) {
    if (job < NJOB_W) {
      float(*t)[65] = (float(*)[65])smraw;
      const int m = job >> 8, rem = job & 255;
      const int n0 = (rem & 15) * 64, k0 = (rem >> 4) * 64;
      const float* src = (m == 0) ? W1
                         : (m <= 8) ? We2 + (size_t)(m - 1) * DIM * DIM
                                    : We3 + (size_t)(m - 9) * DIM * DIM;
      bf16_t* dst = Wt + (size_t)m * DIM * DIM;
      const int r = tid >> 4, c4 = (tid & 15) * 4;
#pragma unroll
      for (int i = 0; i < 4; i++) {
        float4 v = *(const float4*)&src[(size_t)(k0 + i * 16 + r) * DIM + n0 + c4];
        t[i * 16 + r][c4] = v.x;
        t[i * 16 + r][c4 + 1] = v.y;
        t[i * 16 + r][c4 + 2] = v.z;
        t[i * 16 + r][c4 + 3] = v.w;
      }
      __syncthreads();
#pragma unroll
      for (int i = 0; i < 4; i++) {
        int rn = i * 16 + r;
        union { bf16_t b[4]; uint2 u; } tmp;
#pragma unroll
        for (int j = 0; j < 4; j++) tmp.b[j] = (bf16_t)t[c4 + j][rn];
        *(uint2*)&dst[(size_t)(n0 + rn) * DIM + k0 + c4] = tmp.u;
      }
      __syncthreads();  // tile buffer reused next job
    } else if (job < NJOB_W + 2) {
      const int which = job - NJOB_W;
      const float* src = which ? Wg3 : Wg2;
      bf16_t* dst = WgP + which * (128 * 8 * 8);
#pragma unroll
      for (int j = 0; j < 4; j++) {
        int d = tid * 4 + j;
        float4 a = *(const float4*)&src[d * 8];
        float4 b = *(const float4*)&src[d * 8 + 4];
        float v[8] = {a.x, a.y, a.z, a.w, b.x, b.y, b.z, b.w};
#pragma unroll
        for (int e = 0; e < 8; e++)
          dst[((d >> 3) * 8 + e) * 8 + (d & 7)] = (bf16_t)v[e];
      }
    } else {
      const int cid = job - NJOB_W - 2;
      size_t i = ((size_t)cid * 256 + tid) * 8;
      float4 a = *(const float4*)&x[i];
      float4 b = *(const float4*)&x[i + 4];
      union { bf16_t h[8]; uint4 u; } t;
      t.h[0] = (bf16_t)a.x; t.h[1] = (bf16_t)a.y; t.h[2] = (bf16_t)a.z; t.h[3] = (bf16_t)a.w;
      t.h[4] = (bf16_t)b.x; t.h[5] = (bf16_t)b.y; t.h[6] = (bf16_t)b.z; t.h[7] = (bf16_t)b.w;
      *(uint4*)&xb[i] = t.u;
    }
  }
}

// ---------------- stage: dense GEMM h = xb@W1t + b1, + sent(h) -------------
__device__ void st_dense(const bf16_t* A, const bf16_t* Bt, const float* bias,
                         bf16_t* out, float* sent, char* smraw) {
  for (int tile = blockIdx.x; tile < 1024; tile += NBLK) {
    bf16_t* As = (bf16_t*)smraw;
    bf16_t* Bs = As + 128 * 64;
    const int tid = threadIdx.x;
    const int lane = tid & 63, wave = tid >> 6;
    const int quad = lane >> 4, l15 = lane & 15;
    const int wr = (wave >> 1) * 64, wc = (wave & 1) * 64;
    const int j_ = tile >> 3;
    const int m0 = ((tile & 7) * 16 + (j_ >> 3)) * 128;  // XCD-aware decode
    const int n0 = (j_ & 7) * 128;
    const int kc = (tid & 7) ^ ((tid >> 3) & 7);
    const int rbase = tid >> 3;

    const bf16_t* gA[4]; const bf16_t* gB[4]; bf16_t* lA[4]; bf16_t* lB[4];
#pragma unroll
    for (int i = 0; i < 4; i++) {
      int r = rbase + 32 * i;
      gA[i] = A + (size_t)(m0 + r) * DIM + kc * 8;
      gB[i] = Bt + (size_t)(n0 + r) * DIM + kc * 8;
      lA[i] = &As[(wave * 64 + 256 * i) * 8];
      lB[i] = &Bs[(wave * 64 + 256 * i) * 8];
    }
    fx4 acc[4][4];
#pragma unroll
    for (int i = 0; i < 4; i++)
#pragma unroll
      for (int j = 0; j < 4; j++) acc[i][j] = (fx4)0.0f;

    for (int k0 = 0; k0 < DIM; k0 += 64) {
#pragma unroll
      for (int i = 0; i < 4; i++) gll16(gA[i] + k0, lA[i]);
#pragma unroll
      for (int i = 0; i < 4; i++) gll16(gB[i] + k0, lB[i]);
      __syncthreads();
#pragma unroll
      for (int s = 0; s < 2; s++) {
        const int pofs = ((s * 4 + quad) ^ (l15 & 7)) << 3;
        bf16x8 av[4], bv[4];
#pragma unroll
        for (int i = 0; i < 4; i++)
          av[i] = *(const bf16x8*)&As[(wr + i * 16 + l15) * 64 + pofs];
#pragma unroll
        for (int j = 0; j < 4; j++)
          bv[j] = *(const bf16x8*)&Bs[(wc + j * 16 + l15) * 64 + pofs];
#pragma unroll
        for (int i = 0; i < 4; i++)
#pragma unroll
          for (int j = 0; j < 4; j++)
            acc[i][j] = __builtin_amdgcn_mfma_f32_16x16x32_bf16(av[i], bv[j], acc[i][j], 0, 0, 0);
      }
      __syncthreads();
    }
    float bb[4], sj[4] = {0.f, 0.f, 0.f, 0.f};
#pragma unroll
    for (int j = 0; j < 4; j++) bb[j] = bias[n0 + wc + j * 16 + l15];
#pragma unroll
    for (int i = 0; i < 4; i++)
#pragma unroll
      for (int r = 0; r < 4; r++) {
        int rowL = wr + i * 16 + quad * 4 + r;  // C/D layout (m89/m91)
#pragma unroll
        for (int j = 0; j < 4; j++) {
          float v = acc[i][j][r] + bb[j];
          sj[j] += v;
          out[(size_t)(m0 + rowL) * DIM + n0 + wc + j * 16 + l15] = (bf16_t)v;
        }
      }
#pragma unroll
    for (int j = 0; j < 4; j++) {
      sj[j] += __shfl_xor(sj[j], 16);
      sj[j] += __shfl_xor(sj[j], 32);
    }
    if (quad == 0) {
#pragma unroll
      for (int j = 0; j < 4; j++)
        atomicAdd(&sent[(m0 >> 11) * DIM + n0 + wc + j * 16 + l15],
                  sj[j] * (1.0f / SEQ));
    }
  }
}

// ---------------- stage: MFMA gating ---------------------------------------
__device__ void st_gate(const bf16_t* act, const bf16_t* WgPx, int* idx,
                        float* gate, char* smraw) {
  for (int job = blockIdx.x; job < 256; job += NBLK) {
    bf16_t* As = (bf16_t*)smraw;           // 64x64 = 8 KB
    bf16_t* WgS = As + 64 * 64;            // 128x64 = 16 KB
    float* L = (float*)(WgS + 128 * 64);   // 64x8 = 2 KB
    const int tid = threadIdx.x;
    const int lane = tid & 63, wave = tid >> 6;
    const int quad = lane >> 4, l15 = lane & 15;
    const int m0 = job * 64;
    const int kc = (tid & 7) ^ ((tid >> 3) & 7);
    const int rbase = tid >> 3;

    // per-lane global addresses (m104/m108 - r4 lesson)
#pragma unroll
    for (int j = 0; j < 4; j++)
      gll16(WgPx + (j * 256 + wave * 64 + lane) * 8, &WgS[(j * 256 + wave * 64) * 8]);

    const bf16_t* gA[2]; bf16_t* lA[2];
#pragma unroll
    for (int i = 0; i < 2; i++) {
      gA[i] = act + (size_t)(m0 + rbase + 32 * i) * DIM + kc * 8;
      lA[i] = &As[wave * 512 + i * 2048];
    }
    fx4 acc = (fx4)0.0f;
    for (int k0 = 0; k0 < DIM; k0 += 64) {
#pragma unroll
      for (int i = 0; i < 2; i++) gll16(gA[i] + k0, lA[i]);
      __syncthreads();
#pragma unroll
      for (int s = 0; s < 2; s++) {
        const int pofs = ((s * 4 + quad) ^ (l15 & 7)) << 3;
        bf16x8 av = *(const bf16x8*)&As[(wave * 16 + l15) * 64 + pofs];
        bf16x8 bv = *(const bf16x8*)&WgS[((k0 >> 3) + s * 4 + quad) * 64 + (l15 & 7) * 8];
        acc = __builtin_amdgcn_mfma_f32_16x16x32_bf16(av, bv, acc, 0, 0, 0);
      }
      __syncthreads();
    }
    if (l15 < 8) {
#pragma unroll
      for (int r = 0; r < 4; r++) L[(wave * 16 + quad * 4 + r) * 8 + l15] = acc[r];
    }
    __syncthreads();
    if (tid < 64) {
      float lg[8];
#pragma unroll
      for (int e = 0; e < 8; e++) lg[e] = L[tid * 8 + e];
      float best = lg[0];
      int bi = 0;
#pragma unroll
      for (int e = 1; e < 8; e++)
        if (lg[e] > best) { best = lg[e]; bi = e; }  // strict >: first max wins
      float s = 0.f;
#pragma unroll
      for (int e = 0; e < 8; e++) s += expf(lg[e] - best);
      idx[m0 + tid] = bi;
      gate[m0 + tid] = 1.0f / s;
    }
    __syncthreads();
  }
}

// ---------------- stage: route ---------------------------------------------
#define DLMAX 2048
__device__ void st_route(const int* idx, int* tok, int* cnt, bf16_t* obuf,
                         char* smraw) {
  for (int e = blockIdx.x; e < 8; e += NBLK) {
    int* wsum = (int*)smraw;
    int* dlist = wsum + 16;
    const int tid = threadIdx.x, lane = tid & 63, wv = tid >> 6;
    const int4* p4 = (const int4*)(idx + tid * 64);
    unsigned long long mask = 0ull;
#pragma unroll 4
    for (int j = 0; j < 16; j++) {
      int4 v = p4[j];
      mask |= (unsigned long long)(v.x == e) << (4 * j);
      mask |= (unsigned long long)(v.y == e) << (4 * j + 1);
      mask |= (unsigned long long)(v.z == e) << (4 * j + 2);
      mask |= (unsigned long long)(v.w == e) << (4 * j + 3);
    }
    int c = __popcll(mask);
    int sc = c;
#pragma unroll
    for (int off = 1; off < 64; off <<= 1) {
      int n = __shfl_up(sc, off);
      if (lane >= off) sc += n;
    }
    if (lane == 63) wsum[wv] = sc;
    __syncthreads();
    int wb = 0, tot = 0;
#pragma unroll
    for (int i = 0; i < 4; i++) {
      int s = wsum[i];
      tot += s;
      if (i < wv) wb += s;
    }
    int pos = wb + sc - c;  // exclusive prefix
    const uint4 z = {0u, 0u, 0u, 0u};
    for (int j = 0; j < 64; j++) {
      if ((mask >> j) & 1ull) {
        int t = tid * 64 + j;
        if (pos < CAP) {
          tok[e * CAP + pos] = t;
        } else {
          int di = pos - CAP;
          if (di < DLMAX) dlist[di] = t;
          else
            for (int k = 0; k < 128; k++) *(uint4*)&obuf[(size_t)t * DIM + k * 8] = z;
        }
        pos++;
      }
    }
    if (tid == 0) cnt[e] = tot < CAP ? tot : CAP;
    __syncthreads();
    int ndl = tot - CAP;
    ndl = ndl < 0 ? 0 : (ndl > DLMAX ? DLMAX : ndl);
    for (int d = tid >> 7; d < ndl; d += 2) {
      int t = dlist[d];
      *(uint4*)&obuf[(size_t)t * DIM + (tid & 127) * 8] = z;
    }
    __syncthreads();
  }
}

// ---------------- stage: expert GEMM ---------------------------------------
__device__ void st_expert(const bf16_t* Ain, const bf16_t* Wt8,
                          const float* be, const int* tok, const int* cnt,
                          const float* gate, const bf16_t* zp, bf16_t* outp,
                          char* smraw) {
  for (int tile = blockIdx.x; tile < 1024; tile += NBLK) {
    const int e = tile & 7;  // XCD-aware: expert = XCD slot
    const int j_ = tile >> 3;
    const int c0 = (j_ >> 3) * 128;
    const int n0 = (j_ & 7) * 128;
    const int count = cnt[e];
    if (c0 >= count) continue;
    const bf16_t* Bt = Wt8 + (size_t)e * DIM * DIM;
    const float* bias = be + (size_t)e * DIM;
    const int* tk = tok + e * CAP;

    bf16_t* As = (bf16_t*)smraw;
    bf16_t* Bs = As + 128 * 64;
    const int tid = threadIdx.x;
    const int lane = tid & 63, wave = tid >> 6;
    const int quad = lane >> 4, l15 = lane & 15;
    const int wr = (wave >> 1) * 64, wc = (wave & 1) * 64;
    const int kc = (tid & 7) ^ ((tid >> 3) & 7);
    const int rbase = tid >> 3;

    const bf16_t* gA[4]; const bf16_t* gB[4]; bf16_t* lA[4]; bf16_t* lB[4];
#pragma unroll
    for (int i = 0; i < 4; i++) {
      int r = rbase + 32 * i;
      int ca = c0 + r;
      gA[i] = (ca < count) ? Ain + (size_t)tk[ca] * DIM + kc * 8 : zp;
      gB[i] = Bt + (size_t)(n0 + r) * DIM + kc * 8;
      lA[i] = &As[(wave * 64 + 256 * i) * 8];
      lB[i] = &Bs[(wave * 64 + 256 * i) * 8];
    }
    fx4 acc[4][4];
#pragma unroll
    for (int i = 0; i < 4; i++)
#pragma unroll
      for (int j = 0; j < 4; j++) acc[i][j] = (fx4)0.0f;

    for (int k0 = 0; k0 < DIM; k0 += 64) {
#pragma unroll
      for (int i = 0; i < 4; i++) gll16(gA[i] + k0, lA[i]);
#pragma unroll
      for (int i = 0; i < 4; i++) gll16(gB[i] + k0, lB[i]);
      __syncthreads();
#pragma unroll
      for (int s = 0; s < 2; s++) {
        const int pofs = ((s * 4 + quad) ^ (l15 & 7)) << 3;
        bf16x8 av[4], bv[4];
#pragma unroll
        for (int i = 0; i < 4; i++)
          av[i] = *(const bf16x8*)&As[(wr + i * 16 + l15) * 64 + pofs];
#pragma unroll
        for (int j = 0; j < 4; j++)
          bv[j] = *(const bf16x8*)&Bs[(wc + j * 16 + l15) * 64 + pofs];
#pragma unroll
        for (int i = 0; i < 4; i++)
#pragma unroll
          for (int j = 0; j < 4; j++)
            acc[i][j] = __builtin_amdgcn_mfma_f32_16x16x32_bf16(av[i], bv[j], acc[i][j], 0, 0, 0);
      }
      __syncthreads();
    }
    float bb[4];
#pragma unroll
    for (int j = 0; j < 4; j++) bb[j] = bias[n0 + wc + j * 16 + l15];
#pragma unroll
    for (int i = 0; i < 4; i++)
#pragma unroll
      for (int r = 0; r < 4; r++) {
        int c = c0 + wr + i * 16 + quad * 4 + r;
        if (c < count) {
          int t = tk[c];
          float g = gate[t];
#pragma unroll
          for (int j = 0; j < 4; j++)
            outp[(size_t)t * DIM + n0 + wc + j * 16 + l15] =
                (bf16_t)((acc[i][j][r] + bb[j]) * g);
        }
      }
  }
}

// ---------------- stage: sent += mean_s(o2) --------------------------------
__device__ void st_reduce(const bf16_t* o2, float* sent) {
  for (int job = blockIdx.x; job < 256; job += NBLK) {
    const int tid = threadIdx.x;
    const int d8 = (tid & 127) * 8;
    const int sg = tid >> 7;
    const int b = job >> 5;
    const int s0 = (job & 31) * 64 + sg * 32;
    float acc[8] = {0.f, 0.f, 0.f, 0.f, 0.f, 0.f, 0.f, 0.f};
    const size_t base = ((size_t)b * SEQ + s0) * DIM + d8;
    for (int i = 0; i < 32; i++) {
      union { bf16_t v[8]; uint4 u; } oo;
      oo.u = *(const uint4*)&o2[base + (size_t)i * DIM];
#pragma unroll
      for (int j = 0; j < 8; j++) acc[j] += (float)oo.v[j];
    }
#pragma unroll
    for (int j = 0; j < 8; j++)
      atomicAdd(&sent[b * DIM + d8 + j], acc[j] * (1.0f / SEQ));
  }
}

// ---------------- stage: loss ----------------------------------------------
__device__ void st_loss(const float* sent, const int* y, float* out,
                        char* smraw) {
  for (int b = blockIdx.x; b < 8; b += NBLK) {
    float* red = (float*)smraw;
    const int tid = threadIdx.x;
    const float* sb = sent + b * DIM;
    float m = -1e30f;
    for (int d = tid; d < DIM; d += 256) m = fmaxf(m, sb[d]);
    red[tid] = m;
    __syncthreads();
    for (int s = 128; s; s >>= 1) {
      if (tid < s) red[tid] = fmaxf(red[tid], red[tid + s]);
      __syncthreads();
    }
    m = red[0];
    __syncthreads();
    float sum = 0.f;
    for (int d = tid; d < DIM; d += 256) sum += expf(sb[d] - m);
    red[tid] = sum;
    __syncthreads();
    for (int s = 128; s; s >>= 1) {
      if (tid < s) red[tid] += red[tid + s];
      __syncthreads();
    }
    if (tid == 0) atomicAdd(out, (m + logf(red[0]) - sb[y[b]]) * (1.0f / BATCH));
    __syncthreads();
  }
}

// ---------------- the mega-kernel ------------------------------------------
__global__ __launch_bounds__(256, 2) void k_mega(
    const float* W1, const float* We2, const float* We3, const float* Wg2,
    const float* Wg3, const float* x, const float* b1, const float* be2,
    const float* be3, const int* y, bf16_t* Wt, bf16_t* WgP, bf16_t* xb,
    bf16_t* h, bf16_t* o1, bf16_t* o2, int* idx, float* gate, int* tok,
    int* cnt, float* sent, bf16_t* zp, int* bars, float* dout) {
  __shared__ alignas(16) char smraw[32768];

  st_prep(W1, We2, We3, Wg2, Wg3, x, Wt, WgP, xb, smraw);
  gbar(bars);
  st_dense(xb, Wt, b1, h, sent, smraw);
  gbar(bars);
  st_gate(h, WgP, idx, gate, smraw);
  gbar(bars);
  st_route(idx, tok, cnt, o1, smraw);
  gbar(bars);
  st_expert(h, Wt + (size_t)1 * DIM * DIM, be2, tok, cnt, gate, zp, o1, smraw);
  gbar(bars);
  st_gate(o1, WgP + 128 * 8 * 8, idx, gate, smraw);
  gbar(bars);
  st_route(idx, tok, cnt, o2, smraw);
  gbar(bars);
  st_expert(o1, Wt + (size_t)9 * DIM * DIM, be3, tok, cnt, gate, zp, o2, smraw);
  gbar(bars);
  st_reduce(o2, sent);
  gbar(bars);
  st_loss(sent, y, dout, smraw);
}

// ---------------------------------------------------------------------------
extern "C" void kernel_launch(void* const* d_in, const int* in_sizes, int n_in,
                              void* d_out, int out_size, void* d_ws, size_t ws_size,
                              hipStream_t stream) {
  (void)in_sizes; (void)n_in; (void)out_size; (void)ws_size;
  const float* x   = (const float*)d_in[0];
  const int*   y   = (const int*)d_in[1];
  const float* W1  = (const float*)d_in[2];
  const float* b1  = (const float*)d_in[3];
  const float* Wg2 = (const float*)d_in[4];
  const float* We2 = (const float*)d_in[5];
  const float* be2 = (const float*)d_in[6];
  const float* Wg3 = (const float*)d_in[7];
  const float* We3 = (const float*)d_in[8];
  const float* be3 = (const float*)d_in[9];

  char* p = (char*)d_ws;
  size_t off = 0;
  auto carve = [&](size_t bytes) -> char* {
    char* r = p + off;
    off += (bytes + 255) & ~(size_t)255;
    return r;
  };
  bf16_t* Wt   = (bf16_t*)carve((size_t)17 * DIM * DIM * 2);  // 0:W1t 1..8:We2t 9..16:We3t
  bf16_t* WgP  = (bf16_t*)carve(2 * 128 * 8 * 8 * 2);         // gate B-frag packs
  bf16_t* h    = (bf16_t*)carve((size_t)TOKS * DIM * 2);
  bf16_t* o1   = (bf16_t*)carve((size_t)TOKS * DIM * 2);
  bf16_t* o2   = (bf16_t*)carve((size_t)TOKS * DIM * 2);  // aliases xb lifetime
  int*    idx  = (int*)carve(TOKS * 4);
  float*  gate = (float*)carve(TOKS * 4);
  int*    tok  = (int*)carve(NEXP * CAP * 4);
  int*    cnt  = (int*)carve(NEXP * 4);
  // --- contiguous zero region: sent, zp, barrier state (single memset) ---
  size_t zoff0 = off;
  float*  sent = (float*)carve(BATCH * DIM * 4);
  bf16_t* zp   = (bf16_t*)carve(4096);
  int*    bars = (int*)carve(256);
  size_t zbytes = off - zoff0;
  bf16_t* xb   = o2;  // x-bf16 dead before o2 is born (route3/expert3)

  hipMemsetAsync(sent, 0, zbytes, stream);  // sent + zp + bars
  hipMemsetAsync(d_out, 0, 4, stream);      // loss accumulates via atomics

  k_mega<<<NBLK, 256, 0, stream>>>(
      W1, We2, We3, Wg2, Wg3, x, b1, be2, be3, y, Wt, WgP, xb, h, o1, o2,
      idx, gate, tok, cnt, sent, zp, bars, (float*)d_out);
}

// Round 11
// 395.542 us; speedup vs baseline: 3.7489x; 2.1541x over previous
//
#include <hip/hip_runtime.h>
#include <hip/hip_bf16.h>
#include <math.h>

// ---------------------------------------------------------------------------
// SimpleMoEModel: dense GEMM -> top1-MoE -> top1-MoE -> residual -> mean ->
// log_softmax -> NLL.  B=8 S=2048 D=1024 E=8, capacity = T/E = 2048.
//
// Round 11: r5 multi-kernel structure (399 us, all bodies verified) with
// dispatch-count surgery only (16 -> 9 dispatches):
//  - no memsets: extra prep block zeroes sent/zp/done; d_out stored directly
//  - k_route zeroes dropped rows via LDS dlist (r6/r7-verified) -> no 32 MB
//    o-buffer memsets, no zero_rows launches
//  - dense epilogue emits sent(h) from registers (r7-verified shfl+atomic)
//  - loss folded into reduce via tail-block + done-counter + __threadfence
//    (coherence pattern verified by r8/r10 soft barriers)
//  - GEMM/gate/route bodies byte-identical to r5 (BK=64, global_load_lds
//    w=16, XOR swizzle, XCD-aware grids; expert FETCH 32.5 MB verified r5)
// Abandoned: mega-kernel (r8 spill / r9 deadlock / r10 2-per-CU starvation),
// GEMM-epilogue logits fusion (r6/r7: unhidden serial tail).
// ---------------------------------------------------------------------------

#define TOKS 16384
#define DIM 1024
#define NEXP 8
#define CAP 2048
#define BATCH 8
#define SEQ 2048

typedef __bf16 bf16_t;
typedef __bf16 bf16x8 __attribute__((ext_vector_type(8)));
typedef float fx4 __attribute__((ext_vector_type(4)));

__device__ __forceinline__ void gll16(const bf16_t* g, bf16_t* l) {
  __builtin_amdgcn_global_load_lds(
      (const __attribute__((address_space(1))) unsigned int*)g,
      (__attribute__((address_space(3))) unsigned int*)l, 16, 0, 0);
}

// ---------------- prep: W transpose+cvt | Wg pack | x cvt | zero-fill ------
#define PW_BLOCKS (17 * 256)
#define CVT_BLOCKS (TOKS * DIM / 8 / 256)
#define PREP_GRID (PW_BLOCKS + 2 + CVT_BLOCKS + 1)
__global__ __launch_bounds__(256) void k_prep(
    const float* __restrict__ W1, const float* __restrict__ We2,
    const float* __restrict__ We3, const float* __restrict__ Wg2,
    const float* __restrict__ Wg3, const float* __restrict__ x,
    bf16_t* __restrict__ Wt, bf16_t* __restrict__ WgP,
    bf16_t* __restrict__ xb, uint4* __restrict__ zreg, int znq) {
  const int id = blockIdx.x;
  const int tid = threadIdx.x;
  if (id < PW_BLOCKS) {
    __shared__ float t[64][65];
    const int m = id >> 8, rem = id & 255;
    const int n0 = (rem & 15) * 64, k0 = (rem >> 4) * 64;
    const float* src = (m == 0) ? W1
                       : (m <= 8) ? We2 + (size_t)(m - 1) * DIM * DIM
                                  : We3 + (size_t)(m - 9) * DIM * DIM;
    bf16_t* dst = Wt + (size_t)m * DIM * DIM;
    const int r = tid >> 4, c4 = (tid & 15) * 4;
#pragma unroll
    for (int i = 0; i < 4; i++) {
      float4 v = *(const float4*)&src[(size_t)(k0 + i * 16 + r) * DIM + n0 + c4];
      t[i * 16 + r][c4] = v.x;
      t[i * 16 + r][c4 + 1] = v.y;
      t[i * 16 + r][c4 + 2] = v.z;
      t[i * 16 + r][c4 + 3] = v.w;
    }
    __syncthreads();
#pragma unroll
    for (int i = 0; i < 4; i++) {
      int rn = i * 16 + r;
      union { bf16_t b[4]; uint2 u; } tmp;
#pragma unroll
      for (int j = 0; j < 4; j++) tmp.b[j] = (bf16_t)t[c4 + j][rn];
      *(uint2*)&dst[(size_t)(n0 + rn) * DIM + k0 + c4] = tmp.u;
    }
  } else if (id < PW_BLOCKS + 2) {
    const int which = id - PW_BLOCKS;
    const float* src = which ? Wg3 : Wg2;
    bf16_t* dst = WgP + which * (128 * 8 * 8);
#pragma unroll
    for (int j = 0; j < 4; j++) {
      int d = tid * 4 + j;
      float4 a = *(const float4*)&src[d * 8];
      float4 b = *(const float4*)&src[d * 8 + 4];
      float v[8] = {a.x, a.y, a.z, a.w, b.x, b.y, b.z, b.w};
#pragma unroll
      for (int e = 0; e < 8; e++)
        dst[((d >> 3) * 8 + e) * 8 + (d & 7)] = (bf16_t)v[e];
    }
  } else if (id < PW_BLOCKS + 2 + CVT_BLOCKS) {
    const int cid = id - PW_BLOCKS - 2;
    size_t i = ((size_t)cid * 256 + tid) * 8;
    float4 a = *(const float4*)&x[i];
    float4 b = *(const float4*)&x[i + 4];
    union { bf16_t h[8]; uint4 u; } t;
    t.h[0] = (bf16_t)a.x; t.h[1] = (bf16_t)a.y; t.h[2] = (bf16_t)a.z; t.h[3] = (bf16_t)a.w;
    t.h[4] = (bf16_t)b.x; t.h[5] = (bf16_t)b.y; t.h[6] = (bf16_t)b.z; t.h[7] = (bf16_t)b.w;
    *(uint4*)&xb[i] = t.u;
  } else {
    // zero-fill region (sent + zp + done), znq uint4 quanta
    const uint4 z = {0u, 0u, 0u, 0u};
    for (int i = tid; i < znq; i += 256) zreg[i] = z;
  }
}

// ---------------- dense GEMM: h = xb@W1t + b1, + fused sent(h) -------------
__global__ __launch_bounds__(256) void k_gemm_dense(
    const bf16_t* __restrict__ A, const bf16_t* __restrict__ Bt,
    const float* __restrict__ bias, bf16_t* __restrict__ out,
    float* __restrict__ sent) {
  __shared__ alignas(16) bf16_t As[128 * 64];
  __shared__ alignas(16) bf16_t Bs[128 * 64];
  const int tid = threadIdx.x;
  const int lane = tid & 63, wave = tid >> 6;
  const int quad = lane >> 4, l15 = lane & 15;
  const int wr = (wave >> 1) * 64, wc = (wave & 1) * 64;
  const int id = blockIdx.x;
  const int j_ = id >> 3;
  const int m0 = ((id & 7) * 16 + (j_ >> 3)) * 128;  // XCD-aware decode
  const int n0 = (j_ & 7) * 128;
  const int kc = (tid & 7) ^ ((tid >> 3) & 7);
  const int rbase = tid >> 3;

  const bf16_t* gA[4]; const bf16_t* gB[4]; bf16_t* lA[4]; bf16_t* lB[4];
#pragma unroll
  for (int i = 0; i < 4; i++) {
    int r = rbase + 32 * i;
    gA[i] = A + (size_t)(m0 + r) * DIM + kc * 8;
    gB[i] = Bt + (size_t)(n0 + r) * DIM + kc * 8;
    lA[i] = &As[(wave * 64 + 256 * i) * 8];
    lB[i] = &Bs[(wave * 64 + 256 * i) * 8];
  }
  fx4 acc[4][4];
#pragma unroll
  for (int i = 0; i < 4; i++)
#pragma unroll
    for (int j = 0; j < 4; j++) acc[i][j] = (fx4)0.0f;

  for (int k0 = 0; k0 < DIM; k0 += 64) {
#pragma unroll
    for (int i = 0; i < 4; i++) gll16(gA[i] + k0, lA[i]);
#pragma unroll
    for (int i = 0; i < 4; i++) gll16(gB[i] + k0, lB[i]);
    __syncthreads();
#pragma unroll
    for (int s = 0; s < 2; s++) {
      const int pofs = ((s * 4 + quad) ^ (l15 & 7)) << 3;
      bf16x8 av[4], bv[4];
#pragma unroll
      for (int i = 0; i < 4; i++)
        av[i] = *(const bf16x8*)&As[(wr + i * 16 + l15) * 64 + pofs];
#pragma unroll
      for (int j = 0; j < 4; j++)
        bv[j] = *(const bf16x8*)&Bs[(wc + j * 16 + l15) * 64 + pofs];
#pragma unroll
      for (int i = 0; i < 4; i++)
#pragma unroll
        for (int j = 0; j < 4; j++)
          acc[i][j] = __builtin_amdgcn_mfma_f32_16x16x32_bf16(av[i], bv[j], acc[i][j], 0, 0, 0);
    }
    __syncthreads();
  }
  float bb[4], sj[4] = {0.f, 0.f, 0.f, 0.f};
#pragma unroll
  for (int j = 0; j < 4; j++) bb[j] = bias[n0 + wc + j * 16 + l15];
#pragma unroll
  for (int i = 0; i < 4; i++)
#pragma unroll
    for (int r = 0; r < 4; r++) {
      int rowL = wr + i * 16 + quad * 4 + r;  // C/D layout (m89/m91)
#pragma unroll
      for (int j = 0; j < 4; j++) {
        float v = acc[i][j][r] + bb[j];
        sj[j] += v;
        out[(size_t)(m0 + rowL) * DIM + n0 + wc + j * 16 + l15] = (bf16_t)v;
      }
    }
  // sent(h): tile rows are batch-uniform; shfl over quads, 1 atomic/col/wave
#pragma unroll
  for (int j = 0; j < 4; j++) {
    sj[j] += __shfl_xor(sj[j], 16);
    sj[j] += __shfl_xor(sj[j], 32);
  }
  if (quad == 0) {
#pragma unroll
    for (int j = 0; j < 4; j++)
      atomicAdd(&sent[(m0 >> 11) * DIM + n0 + wc + j * 16 + l15],
                sj[j] * (1.0f / SEQ));
  }
}

// ---------------- MFMA gating (r5-verified) --------------------------------
__global__ __launch_bounds__(256) void k_gate_mm(
    const bf16_t* __restrict__ act, const bf16_t* __restrict__ WgPx,
    int* __restrict__ idx, float* __restrict__ gate) {
  __shared__ alignas(16) bf16_t As[64 * 64];    // 8 KB
  __shared__ alignas(16) bf16_t WgS[128 * 64];  // 16 KB
  __shared__ float L[64][8];
  const int tid = threadIdx.x;
  const int lane = tid & 63, wave = tid >> 6;
  const int quad = lane >> 4, l15 = lane & 15;
  const int m0 = blockIdx.x * 64;
  const int kc = (tid & 7) ^ ((tid >> 3) & 7);
  const int rbase = tid >> 3;

  // per-lane global addresses (m104/m108 - r4 lesson)
#pragma unroll
  for (int j = 0; j < 4; j++)
    gll16(WgPx + (j * 256 + wave * 64 + lane) * 8, &WgS[(j * 256 + wave * 64) * 8]);

  const bf16_t* gA[2]; bf16_t* lA[2];
#pragma unroll
  for (int i = 0; i < 2; i++) {
    gA[i] = act + (size_t)(m0 + rbase + 32 * i) * DIM + kc * 8;
    lA[i] = &As[wave * 512 + i * 2048];
  }
  fx4 acc = (fx4)0.0f;
  for (int k0 = 0; k0 < DIM; k0 += 64) {
#pragma unroll
    for (int i = 0; i < 2; i++) gll16(gA[i] + k0, lA[i]);
    __syncthreads();
#pragma unroll
    for (int s = 0; s < 2; s++) {
      const int pofs = ((s * 4 + quad) ^ (l15 & 7)) << 3;
      bf16x8 av = *(const bf16x8*)&As[(wave * 16 + l15) * 64 + pofs];
      bf16x8 bv = *(const bf16x8*)&WgS[((k0 >> 3) + s * 4 + quad) * 64 + (l15 & 7) * 8];
      acc = __builtin_amdgcn_mfma_f32_16x16x32_bf16(av, bv, acc, 0, 0, 0);
    }
    __syncthreads();
  }
  if (l15 < 8) {
#pragma unroll
    for (int r = 0; r < 4; r++) L[wave * 16 + quad * 4 + r][l15] = acc[r];
  }
  __syncthreads();
  if (tid < 64) {
    float lg[8];
#pragma unroll
    for (int e = 0; e < 8; e++) lg[e] = L[tid][e];
    float best = lg[0];
    int bi = 0;
#pragma unroll
    for (int e = 1; e < 8; e++)
      if (lg[e] > best) { best = lg[e]; bi = e; }  // strict >: first max wins
    float s = 0.f;
#pragma unroll
    for (int e = 0; e < 8; e++) s += expf(lg[e] - best);
    idx[m0 + tid] = bi;
    gate[m0 + tid] = 1.0f / s;
  }
}

// ---------------- route: tok list + capacity drop + zero dropped rows ------
#define DLMAX 2048
__global__ __launch_bounds__(1024) void k_route(
    const int* __restrict__ idx, int* __restrict__ tok, int* __restrict__ cnt,
    bf16_t* __restrict__ obuf) {
  const int e = blockIdx.x;
  const int tid = threadIdx.x, lane = tid & 63, wv = tid >> 6;
  __shared__ int wsum[16];
  __shared__ int dlist[DLMAX];
  const int4* p = (const int4*)(idx + tid * 16);
  int m[16];
  int c = 0;
#pragma unroll
  for (int j = 0; j < 4; j++) {
    int4 v = p[j];
    m[j * 4 + 0] = (v.x == e);
    m[j * 4 + 1] = (v.y == e);
    m[j * 4 + 2] = (v.z == e);
    m[j * 4 + 3] = (v.w == e);
    c += m[j * 4] + m[j * 4 + 1] + m[j * 4 + 2] + m[j * 4 + 3];
  }
  int sc = c;  // intra-wave inclusive scan
#pragma unroll
  for (int off = 1; off < 64; off <<= 1) {
    int n = __shfl_up(sc, off);
    if (lane >= off) sc += n;
  }
  if (lane == 63) wsum[wv] = sc;
  __syncthreads();
  int wb = 0, tot = 0;
#pragma unroll
  for (int i = 0; i < 16; i++) {
    int s = wsum[i];
    tot += s;
    if (i < wv) wb += s;
  }
  int pos = wb + sc - c;  // exclusive prefix
  const uint4 z = {0u, 0u, 0u, 0u};
#pragma unroll
  for (int j = 0; j < 16; j++) {
    if (m[j]) {
      int t = tid * 16 + j;
      if (pos < CAP) {
        tok[e * CAP + pos] = t;
      } else {
        int di = pos - CAP;
        if (di < DLMAX) dlist[di] = t;
        else  // pathological overflow: zero directly
          for (int k = 0; k < 128; k++) *(uint4*)&obuf[(size_t)t * DIM + k * 8] = z;
      }
      pos++;
    }
  }
  if (tid == 0) cnt[e] = tot < CAP ? tot : CAP;
  __syncthreads();
  int ndl = tot - CAP;
  ndl = ndl < 0 ? 0 : (ndl > DLMAX ? DLMAX : ndl);
  for (int d = tid >> 7; d < ndl; d += 8) {  // 128 thr/row, 8 rows at a time
    int t = dlist[d];
    *(uint4*)&obuf[(size_t)t * DIM + (tid & 127) * 8] = z;
  }
}

// ---------------- expert GEMM (r5-verified, lean epilogue) -----------------
__global__ __launch_bounds__(256) void k_gemm_expert(
    const bf16_t* __restrict__ Ain, const bf16_t* __restrict__ Wt8,
    const float* __restrict__ be, const int* __restrict__ tok,
    const int* __restrict__ cnt, const float* __restrict__ gate,
    const bf16_t* __restrict__ zp, bf16_t* __restrict__ outp) {
  const int id = blockIdx.x;
  const int e = id & 7;  // XCD-aware: expert = XCD slot (weights L2-resident)
  const int j_ = id >> 3;
  const int c0 = (j_ >> 3) * 128;
  const int n0 = (j_ & 7) * 128;
  const int count = cnt[e];
  if (c0 >= count) return;
  const bf16_t* Bt = Wt8 + (size_t)e * DIM * DIM;
  const float* bias = be + (size_t)e * DIM;
  const int* tk = tok + e * CAP;

  __shared__ alignas(16) bf16_t As[128 * 64];
  __shared__ alignas(16) bf16_t Bs[128 * 64];
  const int tid = threadIdx.x;
  const int lane = tid & 63, wave = tid >> 6;
  const int quad = lane >> 4, l15 = lane & 15;
  const int wr = (wave >> 1) * 64, wc = (wave & 1) * 64;
  const int kc = (tid & 7) ^ ((tid >> 3) & 7);
  const int rbase = tid >> 3;

  const bf16_t* gA[4]; const bf16_t* gB[4]; bf16_t* lA[4]; bf16_t* lB[4];
#pragma unroll
  for (int i = 0; i < 4; i++) {
    int r = rbase + 32 * i;
    int ca = c0 + r;
    gA[i] = (ca < count) ? Ain + (size_t)tk[ca] * DIM + kc * 8 : zp;
    gB[i] = Bt + (size_t)(n0 + r) * DIM + kc * 8;
    lA[i] = &As[(wave * 64 + 256 * i) * 8];
    lB[i] = &Bs[(wave * 64 + 256 * i) * 8];
  }
  fx4 acc[4][4];
#pragma unroll
  for (int i = 0; i < 4; i++)
#pragma unroll
    for (int j = 0; j < 4; j++) acc[i][j] = (fx4)0.0f;

  for (int k0 = 0; k0 < DIM; k0 += 64) {
#pragma unroll
    for (int i = 0; i < 4; i++) gll16(gA[i] + k0, lA[i]);
#pragma unroll
    for (int i = 0; i < 4; i++) gll16(gB[i] + k0, lB[i]);
    __syncthreads();
#pragma unroll
    for (int s = 0; s < 2; s++) {
      const int pofs = ((s * 4 + quad) ^ (l15 & 7)) << 3;
      bf16x8 av[4], bv[4];
#pragma unroll
      for (int i = 0; i < 4; i++)
        av[i] = *(const bf16x8*)&As[(wr + i * 16 + l15) * 64 + pofs];
#pragma unroll
      for (int j = 0; j < 4; j++)
        bv[j] = *(const bf16x8*)&Bs[(wc + j * 16 + l15) * 64 + pofs];
#pragma unroll
      for (int i = 0; i < 4; i++)
#pragma unroll
        for (int j = 0; j < 4; j++)
          acc[i][j] = __builtin_amdgcn_mfma_f32_16x16x32_bf16(av[i], bv[j], acc[i][j], 0, 0, 0);
    }
    __syncthreads();
  }
  float bb[4];
#pragma unroll
  for (int j = 0; j < 4; j++) bb[j] = bias[n0 + wc + j * 16 + l15];
#pragma unroll
  for (int i = 0; i < 4; i++)
#pragma unroll
    for (int r = 0; r < 4; r++) {
      int c = c0 + wr + i * 16 + quad * 4 + r;
      if (c < count) {
        int t = tk[c];
        float g = gate[t];
#pragma unroll
        for (int j = 0; j < 4; j++)
          outp[(size_t)t * DIM + n0 + wc + j * 16 + l15] =
              (bf16_t)((acc[i][j][r] + bb[j]) * g);
      }
    }
}

// ---------------- reduce(o2) + tail-block loss -----------------------------
__global__ __launch_bounds__(256) void k_reduce_loss(
    const bf16_t* __restrict__ o2, float* __restrict__ sent,
    const int* __restrict__ y, int* __restrict__ done,
    float* __restrict__ out) {
  const int tid = threadIdx.x;
  {
    const int job = blockIdx.x;  // 256 jobs: b = job>>5, s-chunk = job&31
    const int d8 = (tid & 127) * 8;
    const int sg = tid >> 7;
    const int b = job >> 5;
    const int s0 = (job & 31) * 64 + sg * 32;
    float acc[8] = {0.f, 0.f, 0.f, 0.f, 0.f, 0.f, 0.f, 0.f};
    const size_t base = ((size_t)b * SEQ + s0) * DIM + d8;
    for (int i = 0; i < 32; i++) {
      union { bf16_t v[8]; uint4 u; } oo;
      oo.u = *(const uint4*)&o2[base + (size_t)i * DIM];
#pragma unroll
      for (int j = 0; j < 8; j++) acc[j] += (float)oo.v[j];
    }
#pragma unroll
    for (int j = 0; j < 8; j++)
      atomicAdd(&sent[b * DIM + d8 + j], acc[j] * (1.0f / SEQ));
  }
  // tail block computes the loss (coherence pattern verified r8/r10)
  __shared__ int isLast;
  __syncthreads();
  if (tid == 0) {
    __threadfence();  // release our sent atomics
    isLast = (atomicAdd(done, 1) == (int)gridDim.x - 1);
  }
  __syncthreads();
  if (!isLast) return;
  __threadfence();  // acquire all blocks' sent updates
  __shared__ float red[256];
  float total = 0.f;
  for (int b = 0; b < BATCH; b++) {
    const float* sb = sent + b * DIM;
    float m = -1e30f;
    for (int d = tid; d < DIM; d += 256) m = fmaxf(m, sb[d]);
    red[tid] = m;
    __syncthreads();
    for (int s = 128; s; s >>= 1) {
      if (tid < s) red[tid] = fmaxf(red[tid], red[tid + s]);
      __syncthreads();
    }
    m = red[0];
    __syncthreads();
    float sum = 0.f;
    for (int d = tid; d < DIM; d += 256) sum += expf(sb[d] - m);
    red[tid] = sum;
    __syncthreads();
    for (int s = 128; s; s >>= 1) {
      if (tid < s) red[tid] += red[tid + s];
      __syncthreads();
    }
    if (tid == 0) total += m + logf(red[0]) - sb[y[b]];
    __syncthreads();
  }
  if (tid == 0) out[0] = total * (1.0f / BATCH);
}

// ---------------------------------------------------------------------------
extern "C" void kernel_launch(void* const* d_in, const int* in_sizes, int n_in,
                              void* d_out, int out_size, void* d_ws, size_t ws_size,
                              hipStream_t stream) {
  (void)in_sizes; (void)n_in; (void)out_size; (void)ws_size;
  const float* x   = (const float*)d_in[0];
  const int*   y   = (const int*)d_in[1];
  const float* W1  = (const float*)d_in[2];
  const float* b1  = (const float*)d_in[3];
  const float* Wg2 = (const float*)d_in[4];
  const float* We2 = (const float*)d_in[5];
  const float* be2 = (const float*)d_in[6];
  const float* Wg3 = (const float*)d_in[7];
  const float* We3 = (const float*)d_in[8];
  const float* be3 = (const float*)d_in[9];

  char* p = (char*)d_ws;
  size_t off = 0;
  auto carve = [&](size_t bytes) -> char* {
    char* r = p + off;
    off += (bytes + 255) & ~(size_t)255;
    return r;
  };
  bf16_t* Wt   = (bf16_t*)carve((size_t)17 * DIM * DIM * 2);  // 0:W1t 1..8:We2t 9..16:We3t
  bf16_t* WgP  = (bf16_t*)carve(2 * 128 * 8 * 8 * 2);         // gate B-frag packs
  bf16_t* h    = (bf16_t*)carve((size_t)TOKS * DIM * 2);
  bf16_t* o1   = (bf16_t*)carve((size_t)TOKS * DIM * 2);
  bf16_t* o2   = (bf16_t*)carve((size_t)TOKS * DIM * 2);  // aliases xb lifetime
  int*    idx  = (int*)carve(TOKS * 4);
  float*  gate = (float*)carve(TOKS * 4);
  int*    tok  = (int*)carve(NEXP * CAP * 4);
  int*    cnt  = (int*)carve(NEXP * 4);
  // --- contiguous zero region (filled by prep's last block) ---
  size_t zoff0 = off;
  float*  sent = (float*)carve(BATCH * DIM * 4);
  bf16_t* zp   = (bf16_t*)carve(4096);
  int*    done = (int*)carve(256);
  size_t zbytes = off - zoff0;
  bf16_t* xb   = o2;  // x-bf16 dead before o2 is born (route3/expert3)

  // prep: W transpose+cvt | Wg pack | x cvt | zero-fill (no memsets needed)
  k_prep<<<PREP_GRID, 256, 0, stream>>>(
      W1, We2, We3, Wg2, Wg3, x, Wt, WgP, xb,
      (uint4*)sent, (int)(zbytes / 16));

  // dense pre-layer (+ fused sent(h))
  k_gemm_dense<<<(TOKS / 128) * (DIM / 128), 256, 0, stream>>>(
      xb, Wt, b1, h, sent);

  // MoE layer 2
  k_gate_mm<<<TOKS / 64, 256, 0, stream>>>(h, WgP, idx, gate);
  k_route<<<NEXP, 1024, 0, stream>>>(idx, tok, cnt, o1);
  k_gemm_expert<<<NEXP * (CAP / 128) * (DIM / 128), 256, 0, stream>>>(
      h, Wt + (size_t)1 * DIM * DIM, be2, tok, cnt, gate, zp, o1);

  // MoE layer 3
  k_gate_mm<<<TOKS / 64, 256, 0, stream>>>(o1, WgP + 128 * 8 * 8, idx, gate);
  k_route<<<NEXP, 1024, 0, stream>>>(idx, tok, cnt, o2);
  k_gemm_expert<<<NEXP * (CAP / 128) * (DIM / 128), 256, 0, stream>>>(
      o1, Wt + (size_t)9 * DIM * DIM, be3, tok, cnt, gate, zp, o2);

  // sent += mean_s(o2); tail block computes CE loss -> d_out
  k_reduce_loss<<<256, 256, 0, stream>>>(o2, sent, y, done, (float*)d_out);
}